// Round 1
// baseline (422.880 us; speedup 1.0000x reference)
//
#include <hip/hip_runtime.h>

#define B_ 4
#define S_ 4096
#define E_ 2048
#define H_ 128

using f32x4 = __attribute__((ext_vector_type(4))) float;
using s16x8 = __attribute__((ext_vector_type(8))) short;

// fp32 -> bf16 bits, round-to-nearest-even
__device__ __forceinline__ short f2bf(float f) {
  unsigned u = __float_as_uint(f);
  u += 0x7FFFu + ((u >> 16) & 1u);
  return (short)(u >> 16);
}

// ---------------------------------------------------------------------------
// Kernel 1: W (E x H fp32) x3 -> Wt (384 x 2048 bf16), row p*128+h holds W_p[:,h]
// ---------------------------------------------------------------------------
__global__ __launch_bounds__(256) void prep_weights(
    const float* __restrict__ Wq, const float* __restrict__ Wk,
    const float* __restrict__ Wv, short* __restrict__ Wt) {
  int p = blockIdx.y;
  const float* W = (p == 0) ? Wq : ((p == 1) ? Wk : Wv);
  int id = blockIdx.x * 256 + threadIdx.x;  // 0 .. E*H-1 (grid.x = 1024)
  int h = id >> 11;                          // / E_
  int e = id & (E_ - 1);
  Wt[(size_t)(p * H_ + h) * E_ + e] = f2bf(W[(size_t)e * H_ + h]);
}

// ---------------------------------------------------------------------------
// Kernel 2: fused QKV projection GEMM.
// C(16384 x 384) = x(16384 x 2048) @ Wt^T ; block = 64 rows x 384 cols, BK=32.
// Wave w: all 4 m-groups (64 rows), n-tiles [w*6, w*6+6) -> cols [w*96, w*96+96).
// ---------------------------------------------------------------------------
__global__ __launch_bounds__(256) void qkv_gemm(
    const float* __restrict__ x, const short* __restrict__ Wt,
    const float* __restrict__ bq, const float* __restrict__ bk,
    const float* __restrict__ bv,
    short* __restrict__ Q, short* __restrict__ K, short* __restrict__ V) {
  // LDS tiles, k-contiguous rows, stride 40 shorts (pad 8 -> 2-way banks = free)
  __shared__ __attribute__((aligned(16))) short xa[64 * 40];
  __shared__ __attribute__((aligned(16))) short wb[384 * 40];

  const int tid = threadIdx.x;
  const int wave = tid >> 6;
  const int lane = tid & 63;
  const int l15 = lane & 15;
  const int quad = lane >> 4;
  const int row0 = blockIdx.x * 64;

  f32x4 acc[4][6];
#pragma unroll
  for (int mg = 0; mg < 4; ++mg)
#pragma unroll
    for (int nt = 0; nt < 6; ++nt) acc[mg][nt] = (f32x4){0.f, 0.f, 0.f, 0.f};

  const int sr = tid >> 2;        // x staging row 0..63
  const int sc4 = (tid & 3) * 8;  // x staging col offset 0,8,16,24

  for (int it = 0; it < 64; ++it) {
    const int k0 = it * 32;
    __syncthreads();
    // stage x tile (fp32 -> bf16)
    {
      const float* xp = x + (size_t)(row0 + sr) * E_ + k0 + sc4;
      float4 f0 = *(const float4*)(xp);
      float4 f1 = *(const float4*)(xp + 4);
      s16x8 xv;
      xv[0] = f2bf(f0.x); xv[1] = f2bf(f0.y); xv[2] = f2bf(f0.z); xv[3] = f2bf(f0.w);
      xv[4] = f2bf(f1.x); xv[5] = f2bf(f1.y); xv[6] = f2bf(f1.z); xv[7] = f2bf(f1.w);
      *(s16x8*)&xa[sr * 40 + sc4] = xv;
    }
    // stage Wt tile (bf16 copy)
#pragma unroll
    for (int i2 = 0; i2 < 6; ++i2) {
      int id = tid + 256 * i2;   // 0..1535
      int r = id >> 2;           // 0..383
      int off = (id & 3) * 8;    // 0..24
      *(s16x8*)&wb[r * 40 + off] =
          *(const s16x8*)(Wt + (size_t)r * E_ + k0 + off);
    }
    __syncthreads();

    s16x8 af[4], bfr[6];
#pragma unroll
    for (int mg = 0; mg < 4; ++mg)
      af[mg] = *(const s16x8*)&xa[(mg * 16 + l15) * 40 + quad * 8];
#pragma unroll
    for (int nt = 0; nt < 6; ++nt)
      bfr[nt] = *(const s16x8*)&wb[(wave * 96 + nt * 16 + l15) * 40 + quad * 8];
#pragma unroll
    for (int mg = 0; mg < 4; ++mg)
#pragma unroll
      for (int nt = 0; nt < 6; ++nt)
        acc[mg][nt] = __builtin_amdgcn_mfma_f32_16x16x32_bf16(
            af[mg], bfr[nt], acc[mg][nt], 0, 0, 0);
  }

  // epilogue: bias + bf16 store into Q/K/V
#pragma unroll
  for (int nt = 0; nt < 6; ++nt) {
    int col = wave * 96 + nt * 16 + l15;
    int p = col >> 7;
    int h = col & (H_ - 1);
    const float* bias = (p == 0) ? bq : ((p == 1) ? bk : bv);
    short* dst = (p == 0) ? Q : ((p == 1) ? K : V);
    float bsv = bias[h];
#pragma unroll
    for (int mg = 0; mg < 4; ++mg)
#pragma unroll
      for (int r = 0; r < 4; ++r) {
        int row = row0 + mg * 16 + quad * 4 + r;
        dst[(size_t)row * H_ + h] = f2bf(acc[mg][nt][r] + bsv);
      }
  }
}

// ---------------------------------------------------------------------------
// Kernel 3: causal flash attention. Block = (qtile of 64 rows, batch).
// 4 waves x 16 q-rows; k-tiles of 64; online softmax; P->A via LDS round-trip.
// ---------------------------------------------------------------------------
__global__ __launch_bounds__(256) void flash_attn(
    const short* __restrict__ Qb, const short* __restrict__ Kb,
    const short* __restrict__ Vb, float* __restrict__ out) {
  __shared__ __attribute__((aligned(16))) short kt_lds[64 * 136];   // [key][h]
  __shared__ __attribute__((aligned(16))) short vt_lds[128 * 72];   // [h][key]
  __shared__ __attribute__((aligned(16))) short p_lds[4 * 16 * 72]; // per-wave P

  const int tid = threadIdx.x;
  const int wave = tid >> 6;
  const int lane = tid & 63;
  const int l15 = lane & 15;
  const int quad = lane >> 4;
  const int qtile = blockIdx.x;
  const int b = blockIdx.y;
  const int q0 = qtile * 64 + wave * 16;
  const size_t bo = (size_t)b * S_ * H_;
  const float scale = 0.08838834764831845f;   // 1/sqrt(128)
  const float L2E = 1.4426950408889634f;

  // Q A-fragments (global, bf16, 16B per lane per kt)
  s16x8 aq[4];
#pragma unroll
  for (int kt = 0; kt < 4; ++kt)
    aq[kt] = *(const s16x8*)(Qb + bo + (size_t)(q0 + l15) * H_ + kt * 32 + quad * 8);

  f32x4 oacc[8];
#pragma unroll
  for (int nt = 0; nt < 8; ++nt) oacc[nt] = (f32x4){0.f, 0.f, 0.f, 0.f};
  float m_r[4], l_r[4];
#pragma unroll
  for (int r = 0; r < 4; ++r) { m_r[r] = -3.0e38f; l_r[r] = 0.f; }

  for (int i = 0; i <= qtile; ++i) {
    const int kb = i * 64;
    __syncthreads();
    // stage K tile [64][128] (coalesced)
#pragma unroll
    for (int i2 = 0; i2 < 4; ++i2) {
      int id = tid + 256 * i2;
      int row = id >> 4;
      int off = (id & 15) * 8;
      *(s16x8*)&kt_lds[row * 136 + off] =
          *(const s16x8*)(Kb + bo + (size_t)(kb + row) * H_ + off);
    }
    // stage V tile transposed -> [h][key]
#pragma unroll
    for (int i2 = 0; i2 < 4; ++i2) {
      int id = tid + 256 * i2;
      int row = id & 63;         // key
      int off = (id >> 6) * 8;   // h base
      s16x8 v = *(const s16x8*)(Vb + bo + (size_t)(kb + row) * H_ + off);
#pragma unroll
      for (int j = 0; j < 8; ++j) vt_lds[(off + j) * 72 + row] = v[j];
    }
    __syncthreads();

    // scores S = Q @ K^T (16 x 64 per wave)
    f32x4 sc[4];
#pragma unroll
    for (int nt = 0; nt < 4; ++nt) {
      f32x4 a = (f32x4){0.f, 0.f, 0.f, 0.f};
#pragma unroll
      for (int kt = 0; kt < 4; ++kt) {
        s16x8 bk2 = *(const s16x8*)&kt_lds[(nt * 16 + l15) * 136 + kt * 32 + quad * 8];
        a = __builtin_amdgcn_mfma_f32_16x16x32_bf16(aq[kt], bk2, a, 0, 0, 0);
      }
#pragma unroll
      for (int r = 0; r < 4; ++r) a[r] *= scale;
      sc[nt] = a;
    }
    if (i == qtile) {  // diagonal tile: causal mask
#pragma unroll
      for (int nt = 0; nt < 4; ++nt)
#pragma unroll
        for (int r = 0; r < 4; ++r)
          if (nt * 16 + l15 > wave * 16 + quad * 4 + r) sc[nt][r] = -3.0e38f;
    }
    // row max (cols live in lanes quad*16..quad*16+15, xor<16 stays in quad)
    float vm[4];
#pragma unroll
    for (int r = 0; r < 4; ++r)
      vm[r] = fmaxf(fmaxf(sc[0][r], sc[1][r]), fmaxf(sc[2][r], sc[3][r]));
#pragma unroll
    for (int off = 1; off < 16; off <<= 1)
#pragma unroll
      for (int r = 0; r < 4; ++r) vm[r] = fmaxf(vm[r], __shfl_xor(vm[r], off));

    float al[4];
#pragma unroll
    for (int r = 0; r < 4; ++r) {
      float mn = fmaxf(m_r[r], vm[r]);
      al[r] = exp2f((m_r[r] - mn) * L2E);
      m_r[r] = mn;
    }
    // p = exp(s - m), row sums
    float rs[4] = {0.f, 0.f, 0.f, 0.f};
#pragma unroll
    for (int nt = 0; nt < 4; ++nt)
#pragma unroll
      for (int r = 0; r < 4; ++r) {
        float pv = exp2f((sc[nt][r] - m_r[r]) * L2E);
        sc[nt][r] = pv;
        rs[r] += pv;
      }
#pragma unroll
    for (int off = 1; off < 16; off <<= 1)
#pragma unroll
      for (int r = 0; r < 4; ++r) rs[r] += __shfl_xor(rs[r], off);
#pragma unroll
    for (int r = 0; r < 4; ++r) l_r[r] = l_r[r] * al[r] + rs[r];
    // rescale output accumulator
#pragma unroll
    for (int nt = 0; nt < 8; ++nt)
#pragma unroll
      for (int r = 0; r < 4; ++r) oacc[nt][r] *= al[r];

    // P (C-layout) -> per-wave LDS -> A-layout bf16
    short* pw = &p_lds[wave * 16 * 72];
#pragma unroll
    for (int nt = 0; nt < 4; ++nt)
#pragma unroll
      for (int r = 0; r < 4; ++r)
        pw[(quad * 4 + r) * 72 + nt * 16 + l15] = f2bf(sc[nt][r]);

    s16x8 ap[2];
#pragma unroll
    for (int kt2 = 0; kt2 < 2; ++kt2)
      ap[kt2] = *(const s16x8*)&pw[l15 * 72 + kt2 * 32 + quad * 8];
    // O += P @ V
#pragma unroll
    for (int nt = 0; nt < 8; ++nt)
#pragma unroll
      for (int kt2 = 0; kt2 < 2; ++kt2) {
        s16x8 bv2 = *(const s16x8*)&vt_lds[(nt * 16 + l15) * 72 + kt2 * 32 + quad * 8];
        oacc[nt] = __builtin_amdgcn_mfma_f32_16x16x32_bf16(ap[kt2], bv2, oacc[nt], 0, 0, 0);
      }
  }

  // epilogue: normalize, fp32 store
  float inv[4];
#pragma unroll
  for (int r = 0; r < 4; ++r) inv[r] = 1.0f / l_r[r];
#pragma unroll
  for (int nt = 0; nt < 8; ++nt)
#pragma unroll
    for (int r = 0; r < 4; ++r)
      out[bo + (size_t)(q0 + quad * 4 + r) * H_ + nt * 16 + l15] =
          oacc[nt][r] * inv[r];
}

// ---------------------------------------------------------------------------
extern "C" void kernel_launch(void* const* d_in, const int* in_sizes, int n_in,
                              void* d_out, int out_size, void* d_ws, size_t ws_size,
                              hipStream_t stream) {
  const float* x  = (const float*)d_in[0];
  const float* Wq = (const float*)d_in[1];
  const float* bq = (const float*)d_in[2];
  const float* Wk = (const float*)d_in[3];
  const float* bk = (const float*)d_in[4];
  const float* Wv = (const float*)d_in[5];
  const float* bv = (const float*)d_in[6];

  // ws layout: Wt (384*2048 bf16) | Q | K | V (each B*S*H bf16)  ~= 13.5 MB
  short* Wt = (short*)d_ws;
  short* Q  = Wt + (size_t)384 * E_;
  short* K  = Q + (size_t)B_ * S_ * H_;
  short* V  = K + (size_t)B_ * S_ * H_;
  float* out = (float*)d_out;

  hipLaunchKernelGGL(prep_weights, dim3(E_ * H_ / 256, 3), dim3(256), 0, stream,
                     Wq, Wk, Wv, Wt);
  hipLaunchKernelGGL(qkv_gemm, dim3((B_ * S_) / 64), dim3(256), 0, stream,
                     x, Wt, bq, bk, bv, Q, K, V);
  hipLaunchKernelGGL(flash_attn, dim3(S_ / 64, B_), dim3(256), 0, stream,
                     Q, K, V, out);
}